// Round 3
// baseline (374.330 us; speedup 1.0000x reference)
//
#include <hip/hip_runtime.h>

typedef _Float16 h16;
typedef _Float16 h16x8 __attribute__((ext_vector_type(8)));
typedef _Float16 h16x4 __attribute__((ext_vector_type(4)));
typedef float f32x4 __attribute__((ext_vector_type(4)));

#define SEQ 2048
#define RSTRIDE 8192   // b*h*d = 4*16*128
#define QTILE 128
#define NQT (SEQ / QTILE)   // 16
#define KBLK 64
#define KPAD 136       // K LDS row stride (halves)
#define VPAD 72        // Vt LDS row stride (halves)

__global__ __launch_bounds__(512, 4)
void fa_fwd_kernel(const float* __restrict__ Qg, const float* __restrict__ Kg,
                   const float* __restrict__ Vg, float* __restrict__ Out)
{
    __shared__ __attribute__((aligned(16))) h16 Kl[KBLK * KPAD];   // [key][d]
    __shared__ __attribute__((aligned(16))) h16 Vt[128 * VPAD];    // [d][key^swz]

    const int bx   = blockIdx.x;     // 0..7, pairs (bx, 15-bx)
    const int bh   = blockIdx.y;
    const int tid  = threadIdx.x;    // 0..511 (8 waves)
    const int wave = tid >> 6;
    const int lane = tid & 63;
    const int lg   = lane >> 4;
    const int lc   = lane & 15;
    const size_t bhoff = (size_t)bh * 128;
    const float NEGINF = -__builtin_inff();
    const float SL = 0.08838834764831845f * 1.4426950408889634f;  // (1/sqrt(128))*log2(e)

    // ---- K staging geometry: 2 iters x (row = tid>>4 + 32*it, 8 floats)
    const int krow = tid >> 4;            // 0..31
    const int kd0  = (tid & 15) * 8;
    const float* kbase = Kg + (size_t)krow * RSTRIDE + bhoff + kd0;
    h16* kwbase = &Kl[krow * KPAD + kd0];

    // ---- V staging geometry: thread owns 4 keys x 4 d's, one pass
    const int vkey0 = 4 * (tid >> 5);     // 0..60
    const int vd0   = 4 * (tid & 31);     // 0..124
    const int vcol  = vkey0 ^ (4 * (tid & 15));   // swz(d) = 4*((d>>2)&15), (d>>2)&15 == tid&15
    const float* vbase = Vg + (size_t)vkey0 * RSTRIDE + bhoff + vd0;

    f32x4 kra[2], krb[2], vra[4];   // prefetch registers (T14)

    for (int half = 0; half < 2; ++half) {
        const int qt = half ? (NQT - 1 - bx) : bx;
        const int q0 = qt * QTILE;
        const int qsbase = q0 + wave * 16;   // this wave's 16 q-rows

        // ---- Q fragments: qf[dk][j] = Q[qrow][32*dk + 8*lg + j]
        h16x8 qf[4];
        {
            const int qrow = qsbase + lc;
            const float* qp = Qg + (size_t)qrow * RSTRIDE + bhoff + lg * 8;
#pragma unroll
            for (int dk = 0; dk < 4; ++dk) {
                f32x4 a = *(const f32x4*)(qp + dk * 32);
                f32x4 b = *(const f32x4*)(qp + dk * 32 + 4);
                h16x8 f;
                f[0] = (h16)a[0]; f[1] = (h16)a[1]; f[2] = (h16)a[2]; f[3] = (h16)a[3];
                f[4] = (h16)b[0]; f[5] = (h16)b[1]; f[6] = (h16)b[2]; f[7] = (h16)b[3];
                qf[dk] = f;
            }
        }

        f32x4 o[8];
#pragma unroll
        for (int dt = 0; dt < 8; ++dt) o[dt] = f32x4{0.f, 0.f, 0.f, 0.f};
        float mreg = NEGINF;
        float lsum = 0.f;

        const int nkv = 2 * (qt + 1);

        // ---- prefetch tile 0 into registers
#pragma unroll
        for (int it = 0; it < 2; ++it) {
            const float* gp = kbase + (size_t)(32 * it) * RSTRIDE;
            kra[it] = *(const f32x4*)gp;
            krb[it] = *(const f32x4*)(gp + 4);
        }
#pragma unroll
        for (int kk = 0; kk < 4; ++kk)
            vra[kk] = *(const f32x4*)(vbase + (size_t)kk * RSTRIDE);

        for (int t = 0; t < nkv; ++t) {
            const int kv0 = t * KBLK;
            __syncthreads();   // previous tile's compute done before overwrite

            // ---- write staged K regs -> LDS (b128)
#pragma unroll
            for (int it = 0; it < 2; ++it) {
                f32x4 a = kra[it], b = krb[it];
                h16x8 f;
                f[0] = (h16)a[0]; f[1] = (h16)a[1]; f[2] = (h16)a[2]; f[3] = (h16)a[3];
                f[4] = (h16)b[0]; f[5] = (h16)b[1]; f[6] = (h16)b[2]; f[7] = (h16)b[3];
                *(h16x8*)(kwbase + it * 32 * KPAD) = f;
            }
            // ---- write staged V regs -> LDS transposed (b64 vector writes)
#pragma unroll
            for (int e = 0; e < 4; ++e) {
                h16x4 wv;
                wv[0] = (h16)vra[0][e]; wv[1] = (h16)vra[1][e];
                wv[2] = (h16)vra[2][e]; wv[3] = (h16)vra[3][e];
                *(h16x4*)&Vt[(vd0 + e) * VPAD + vcol] = wv;
            }
            __syncthreads();

            // ---- issue next tile's global loads (hide under compute below)
            if (t + 1 < nkv) {
                const size_t toff = (size_t)(kv0 + KBLK) * RSTRIDE;
#pragma unroll
                for (int it = 0; it < 2; ++it) {
                    const float* gp = kbase + toff + (size_t)(32 * it) * RSTRIDE;
                    kra[it] = *(const f32x4*)gp;
                    krb[it] = *(const f32x4*)(gp + 4);
                }
#pragma unroll
                for (int kk = 0; kk < 4; ++kk)
                    vra[kk] = *(const f32x4*)(vbase + toff + (size_t)kk * RSTRIDE);
            }

            // ---- compute: one 16-row strip per wave
            if (kv0 <= qsbase + 15) {          // wave-uniform skip
                const int qrow = qsbase + lc;

                // S^T = K . Q^T : sacc[kt] holds keys kv0+16*kt+4*lg+r, q col = lc
                f32x4 sacc[4];
#pragma unroll
                for (int kt = 0; kt < 4; ++kt) sacc[kt] = f32x4{0.f, 0.f, 0.f, 0.f};
#pragma unroll
                for (int kt = 0; kt < 4; ++kt) {
#pragma unroll
                    for (int dk = 0; dk < 4; ++dk) {
                        h16x8 a = *(const h16x8*)&Kl[(lc + 16 * kt) * KPAD + dk * 32 + lg * 8];
                        sacc[kt] = __builtin_amdgcn_mfma_f32_16x16x32_f16(a, qf[dk], sacc[kt], 0, 0, 0);
                    }
                }

                // online softmax (in place in sacc)
                float vmax = NEGINF;
#pragma unroll
                for (int kt = 0; kt < 4; ++kt) {
#pragma unroll
                    for (int r = 0; r < 4; ++r) {
                        float sv = sacc[kt][r] * SL;
                        const int key = kv0 + 16 * kt + 4 * lg + r;
                        sv = (key <= qrow) ? sv : NEGINF;
                        sacc[kt][r] = sv;
                        vmax = fmaxf(vmax, sv);
                    }
                }
                vmax = fmaxf(vmax, __shfl_xor(vmax, 16, 64));
                vmax = fmaxf(vmax, __shfl_xor(vmax, 32, 64));
                const float mnew  = fmaxf(mreg, vmax);
                const float alpha = __builtin_exp2f(mreg - mnew);
                mreg = mnew;
                float psum = 0.f;
#pragma unroll
                for (int kt = 0; kt < 4; ++kt)
#pragma unroll
                    for (int r = 0; r < 4; ++r) {
                        const float e = __builtin_exp2f(sacc[kt][r] - mnew);
                        sacc[kt][r] = e;
                        psum += e;
                    }
                psum += __shfl_xor(psum, 16, 64);
                psum += __shfl_xor(psum, 32, 64);
                lsum = lsum * alpha + psum;

                // rescale O (alpha owner lane = 4*lg+r)
#pragma unroll
                for (int r = 0; r < 4; ++r) {
                    const float ar = __shfl(alpha, 4 * lg + r, 64);
#pragma unroll
                    for (int dt = 0; dt < 8; ++dt) o[dt][r] *= ar;
                }

                // P fragments (in-lane via k-slot bijection: key = 32u+4g+(j&3)+16*(j>>2))
                h16x8 pa[2];
#pragma unroll
                for (int u = 0; u < 2; ++u) {
                    h16x8 f;
                    f[0] = (h16)sacc[2 * u][0];     f[1] = (h16)sacc[2 * u][1];
                    f[2] = (h16)sacc[2 * u][2];     f[3] = (h16)sacc[2 * u][3];
                    f[4] = (h16)sacc[2 * u + 1][0]; f[5] = (h16)sacc[2 * u + 1][1];
                    f[6] = (h16)sacc[2 * u + 1][2]; f[7] = (h16)sacc[2 * u + 1][3];
                    pa[u] = f;
                }

                // PV: O[q][dcol] += P . V
#pragma unroll
                for (int dt = 0; dt < 8; ++dt) {
                    const int dcol = lc + 16 * dt;
                    const int swz  = ((dcol >> 2) & 15) << 2;
                    const h16* vrow = &Vt[dcol * VPAD];
#pragma unroll
                    for (int u = 0; u < 2; ++u) {
                        union { h16x8 v8; h16x4 v4[2]; } bv;
                        bv.v4[0] = *(const h16x4*)&vrow[(32 * u + 4 * lg) ^ swz];
                        bv.v4[1] = *(const h16x4*)&vrow[(32 * u + 16 + 4 * lg) ^ swz];
                        o[dt] = __builtin_amdgcn_mfma_f32_16x16x32_f16(pa[u], bv.v8, o[dt], 0, 0, 0);
                    }
                }
            }
        } // kv tiles

        // ---- epilogue
#pragma unroll
        for (int r = 0; r < 4; ++r) {
            const float lr  = __shfl(lsum, 4 * lg + r, 64);
            const float inv = 1.0f / lr;
            const int qrow  = qsbase + 4 * lg + r;
            float* op = Out + (size_t)qrow * RSTRIDE + bhoff + lc;
#pragma unroll
            for (int dt = 0; dt < 8; ++dt) op[dt * 16] = o[dt][r] * inv;
        }
    } // half
}

extern "C" void kernel_launch(void* const* d_in, const int* in_sizes, int n_in,
                              void* d_out, int out_size, void* d_ws, size_t ws_size,
                              hipStream_t stream) {
    (void)in_sizes; (void)n_in; (void)out_size; (void)d_ws; (void)ws_size;
    const float* Q = (const float*)d_in[0];
    const float* K = (const float*)d_in[1];
    const float* V = (const float*)d_in[2];
    float* O = (float*)d_out;
    dim3 grid(NQT / 2, 64);
    fa_fwd_kernel<<<grid, 512, 0, stream>>>(Q, K, V, O);
}

// Round 4
// 155.645 us; speedup vs baseline: 2.4050x; 2.4050x over previous
//
#include <hip/hip_runtime.h>

typedef _Float16 h16;
typedef _Float16 h16x8 __attribute__((ext_vector_type(8)));
typedef _Float16 h16x4 __attribute__((ext_vector_type(4)));
typedef float f32x4 __attribute__((ext_vector_type(4)));

#define SEQ 2048
#define RSTRIDE 8192   // b*h*d = 4*16*128
#define QTILE 128
#define NQT (SEQ / QTILE)   // 16
#define KBLK 64
#define KPAD 136       // K LDS row stride (halves)
#define VPAD 72        // Vt LDS row stride (halves)

__global__ __launch_bounds__(512, 2)
void fa_fwd_kernel(const float* __restrict__ Qg, const float* __restrict__ Kg,
                   const float* __restrict__ Vg, float* __restrict__ Out)
{
    // double-buffered: 71.7 KB total -> 2 blocks/CU
    __shared__ __attribute__((aligned(16))) h16 Kl[2][KBLK * KPAD];   // [key][d]
    __shared__ __attribute__((aligned(16))) h16 Vt[2][128 * VPAD];    // [d][key^swz]

    // XCD-aware remap: each XCD gets 8 contiguous bh (K/V locality in its L2)
    const int lin = (int)blockIdx.x + 8 * (int)blockIdx.y;   // 0..511
    const int xsw = (lin & 7) * 64 + (lin >> 3);             // bijective
    const int bx  = xsw & 7;        // 0..7, pairs (bx, 15-bx)
    const int bh  = xsw >> 3;       // 0..63
    const int tid  = threadIdx.x;   // 0..511 (8 waves)
    const int wave = tid >> 6;
    const int lane = tid & 63;
    const int lg   = lane >> 4;
    const int lc   = lane & 15;
    const size_t bhoff = (size_t)bh * 128;
    const float NEGINF = -__builtin_inff();
    const float SL = 0.08838834764831845f * 1.4426950408889634f;  // (1/sqrt(128))*log2(e)

    // ---- K staging geometry: 2 iters x (row = tid>>4 + 32*it, 8 floats)
    const int krow = tid >> 4;            // 0..31
    const int kd0  = (tid & 15) * 8;
    const float* kbase = Kg + (size_t)krow * RSTRIDE + bhoff + kd0;
    const int kwoff = krow * KPAD + kd0;

    // ---- V staging geometry: thread owns 4 keys x 4 d's, one pass
    const int vkey0 = 4 * (tid >> 5);     // 0..60
    const int vd0   = 4 * (tid & 31);     // 0..124
    const int vcol  = vkey0 ^ (4 * (tid & 15));   // swz(d)=4*((d>>2)&15) == 4*(tid&15)
    const float* vbase = Vg + (size_t)vkey0 * RSTRIDE + bhoff + vd0;

    f32x4 kra[2], krb[2], vra[4];   // prefetch registers (T14)

    for (int half = 0; half < 2; ++half) {
        const int qt = half ? (NQT - 1 - bx) : bx;
        const int q0 = qt * QTILE;
        const int qsbase = q0 + wave * 16;   // this wave's 16 q-rows

        // ---- Q fragments: qf[dk][j] = Q[qrow][32*dk + 8*lg + j]
        h16x8 qf[4];
        {
            const int qrow = qsbase + lc;
            const float* qp = Qg + (size_t)qrow * RSTRIDE + bhoff + lg * 8;
#pragma unroll
            for (int dk = 0; dk < 4; ++dk) {
                f32x4 a = *(const f32x4*)(qp + dk * 32);
                f32x4 b = *(const f32x4*)(qp + dk * 32 + 4);
                h16x8 f;
                f[0] = (h16)a[0]; f[1] = (h16)a[1]; f[2] = (h16)a[2]; f[3] = (h16)a[3];
                f[4] = (h16)b[0]; f[5] = (h16)b[1]; f[6] = (h16)b[2]; f[7] = (h16)b[3];
                qf[dk] = f;
            }
        }

        f32x4 o[8];
#pragma unroll
        for (int dt = 0; dt < 8; ++dt) o[dt] = f32x4{0.f, 0.f, 0.f, 0.f};
        float mreg = NEGINF;
        float lsum = 0.f;

        const int nkv = 2 * (qt + 1);

        // ---- prologue: load t0 -> regs, write buf0, load t1 -> regs, barrier
#pragma unroll
        for (int it = 0; it < 2; ++it) {
            const float* gp = kbase + (size_t)(32 * it) * RSTRIDE;
            kra[it] = *(const f32x4*)gp;
            krb[it] = *(const f32x4*)(gp + 4);
        }
#pragma unroll
        for (int kk = 0; kk < 4; ++kk)
            vra[kk] = *(const f32x4*)(vbase + (size_t)kk * RSTRIDE);
        __syncthreads();   // previous half's compute fully done before overwrite
        {
            h16* kw = &Kl[0][kwoff];
#pragma unroll
            for (int it = 0; it < 2; ++it) {
                f32x4 a = kra[it], b = krb[it];
                h16x8 f;
                f[0] = (h16)a[0]; f[1] = (h16)a[1]; f[2] = (h16)a[2]; f[3] = (h16)a[3];
                f[4] = (h16)b[0]; f[5] = (h16)b[1]; f[6] = (h16)b[2]; f[7] = (h16)b[3];
                *(h16x8*)(kw + it * 32 * KPAD) = f;
            }
#pragma unroll
            for (int e = 0; e < 4; ++e) {
                h16x4 wv;
                wv[0] = (h16)vra[0][e]; wv[1] = (h16)vra[1][e];
                wv[2] = (h16)vra[2][e]; wv[3] = (h16)vra[3][e];
                *(h16x4*)&Vt[0][(vd0 + e) * VPAD + vcol] = wv;
            }
        }
        if (nkv > 1) {
            const size_t toff = (size_t)KBLK * RSTRIDE;
#pragma unroll
            for (int it = 0; it < 2; ++it) {
                const float* gp = kbase + toff + (size_t)(32 * it) * RSTRIDE;
                kra[it] = *(const f32x4*)gp;
                krb[it] = *(const f32x4*)(gp + 4);
            }
#pragma unroll
            for (int kk = 0; kk < 4; ++kk)
                vra[kk] = *(const f32x4*)(vbase + toff + (size_t)kk * RSTRIDE);
        }
        __syncthreads();   // buf0 visible

        for (int t = 0; t < nkv; ++t) {
            const int kv0 = t * KBLK;
            const int cb = t & 1;

            // ---- write staged regs (tile t+1) -> other buffer (overlaps compute below)
            if (t + 1 < nkv) {
                h16* kw = &Kl[cb ^ 1][kwoff];
#pragma unroll
                for (int it = 0; it < 2; ++it) {
                    f32x4 a = kra[it], b = krb[it];
                    h16x8 f;
                    f[0] = (h16)a[0]; f[1] = (h16)a[1]; f[2] = (h16)a[2]; f[3] = (h16)a[3];
                    f[4] = (h16)b[0]; f[5] = (h16)b[1]; f[6] = (h16)b[2]; f[7] = (h16)b[3];
                    *(h16x8*)(kw + it * 32 * KPAD) = f;
                }
#pragma unroll
                for (int e = 0; e < 4; ++e) {
                    h16x4 wv;
                    wv[0] = (h16)vra[0][e]; wv[1] = (h16)vra[1][e];
                    wv[2] = (h16)vra[2][e]; wv[3] = (h16)vra[3][e];
                    *(h16x4*)&Vt[cb ^ 1][(vd0 + e) * VPAD + vcol] = wv;
                }
            }
            // ---- issue tile t+2 global loads (land during compute of t, t+1)
            if (t + 2 < nkv) {
                const size_t toff = (size_t)(kv0 + 2 * KBLK) * RSTRIDE;
#pragma unroll
                for (int it = 0; it < 2; ++it) {
                    const float* gp = kbase + toff + (size_t)(32 * it) * RSTRIDE;
                    kra[it] = *(const f32x4*)gp;
                    krb[it] = *(const f32x4*)(gp + 4);
                }
#pragma unroll
                for (int kk = 0; kk < 4; ++kk)
                    vra[kk] = *(const f32x4*)(vbase + toff + (size_t)kk * RSTRIDE);
            }

            // ---- compute: one 16-row strip per wave
            if (kv0 <= qsbase + 15) {          // wave-uniform skip
                const int qrow = qsbase + lc;
                const h16* Kc = Kl[cb];
                const h16* Vc = Vt[cb];

                // S^T = K . Q^T : sacc[kt] holds keys kv0+16*kt+4*lg+r, q col = lc
                f32x4 sacc[4];
#pragma unroll
                for (int kt = 0; kt < 4; ++kt) sacc[kt] = f32x4{0.f, 0.f, 0.f, 0.f};
#pragma unroll
                for (int kt = 0; kt < 4; ++kt) {
#pragma unroll
                    for (int dk = 0; dk < 4; ++dk) {
                        h16x8 a = *(const h16x8*)&Kc[(lc + 16 * kt) * KPAD + dk * 32 + lg * 8];
                        sacc[kt] = __builtin_amdgcn_mfma_f32_16x16x32_f16(a, qf[dk], sacc[kt], 0, 0, 0);
                    }
                }

                // online softmax (in place in sacc)
                float vmax = NEGINF;
#pragma unroll
                for (int kt = 0; kt < 4; ++kt) {
#pragma unroll
                    for (int r = 0; r < 4; ++r) {
                        float sv = sacc[kt][r] * SL;
                        const int key = kv0 + 16 * kt + 4 * lg + r;
                        sv = (key <= qrow) ? sv : NEGINF;
                        sacc[kt][r] = sv;
                        vmax = fmaxf(vmax, sv);
                    }
                }
                vmax = fmaxf(vmax, __shfl_xor(vmax, 16, 64));
                vmax = fmaxf(vmax, __shfl_xor(vmax, 32, 64));
                const float mnew  = fmaxf(mreg, vmax);
                const float alpha = __builtin_exp2f(mreg - mnew);
                mreg = mnew;
                float psum = 0.f;
#pragma unroll
                for (int kt = 0; kt < 4; ++kt)
#pragma unroll
                    for (int r = 0; r < 4; ++r) {
                        const float e = __builtin_exp2f(sacc[kt][r] - mnew);
                        sacc[kt][r] = e;
                        psum += e;
                    }
                psum += __shfl_xor(psum, 16, 64);
                psum += __shfl_xor(psum, 32, 64);
                lsum = lsum * alpha + psum;

                // rescale O (alpha owner lane = 4*lg+r)
#pragma unroll
                for (int r = 0; r < 4; ++r) {
                    const float ar = __shfl(alpha, 4 * lg + r, 64);
#pragma unroll
                    for (int dt = 0; dt < 8; ++dt) o[dt][r] *= ar;
                }

                // P fragments (in-lane via k-slot bijection: key = 32u+4g+(j&3)+16*(j>>2))
                h16x8 pa[2];
#pragma unroll
                for (int u = 0; u < 2; ++u) {
                    h16x8 f;
                    f[0] = (h16)sacc[2 * u][0];     f[1] = (h16)sacc[2 * u][1];
                    f[2] = (h16)sacc[2 * u][2];     f[3] = (h16)sacc[2 * u][3];
                    f[4] = (h16)sacc[2 * u + 1][0]; f[5] = (h16)sacc[2 * u + 1][1];
                    f[6] = (h16)sacc[2 * u + 1][2]; f[7] = (h16)sacc[2 * u + 1][3];
                    pa[u] = f;
                }

                // PV: O[q][dcol] += P . V
#pragma unroll
                for (int dt = 0; dt < 8; ++dt) {
                    const int dcol = lc + 16 * dt;
                    const int swz  = ((dcol >> 2) & 15) << 2;
                    const h16* vrow = &Vc[dcol * VPAD];
#pragma unroll
                    for (int u = 0; u < 2; ++u) {
                        union { h16x8 v8; h16x4 v4[2]; } bv;
                        bv.v4[0] = *(const h16x4*)&vrow[(32 * u + 4 * lg) ^ swz];
                        bv.v4[1] = *(const h16x4*)&vrow[(32 * u + 16 + 4 * lg) ^ swz];
                        o[dt] = __builtin_amdgcn_mfma_f32_16x16x32_f16(pa[u], bv.v8, o[dt], 0, 0, 0);
                    }
                }
            }
            __syncthreads();   // single barrier per tile: buf (t+1) written, buf t consumed
        } // kv tiles

        // ---- epilogue
#pragma unroll
        for (int r = 0; r < 4; ++r) {
            const float lr  = __shfl(lsum, 4 * lg + r, 64);
            const float inv = 1.0f / lr;
            const int qrow  = qsbase + 4 * lg + r;
            float* op = Out + (size_t)qrow * RSTRIDE + bhoff + lc;
#pragma unroll
            for (int dt = 0; dt < 8; ++dt) op[dt * 16] = o[dt][r] * inv;
        }
    } // half
}

extern "C" void kernel_launch(void* const* d_in, const int* in_sizes, int n_in,
                              void* d_out, int out_size, void* d_ws, size_t ws_size,
                              hipStream_t stream) {
    (void)in_sizes; (void)n_in; (void)out_size; (void)d_ws; (void)ws_size;
    const float* Q = (const float*)d_in[0];
    const float* K = (const float*)d_in[1];
    const float* V = (const float*)d_in[2];
    float* O = (float*)d_out;
    dim3 grid(NQT / 2, 64);
    fa_fwd_kernel<<<grid, 512, 0, stream>>>(Q, K, V, O);
}